// Round 1
// baseline (336.850 us; speedup 1.0000x reference)
//
#include <hip/hip_runtime.h>
#include <hip/hip_bf16.h>

typedef __bf16 bf16x8 __attribute__((ext_vector_type(8)));
typedef __bf16 bf16x4 __attribute__((ext_vector_type(4)));
typedef float  f32x4  __attribute__((ext_vector_type(4)));

#define K_DIM 1024
#define N_DIM 1024
// fallback tile
#define BM 128
#define BN 128
#define BK 64
// pipelined tile
#define BM2 256
#define BN2 256
#define BK2 32
#define PDEPTH 4
#define NT2 (K_DIM / BK2)

typedef unsigned int u32;
typedef u32 __attribute__((address_space(1))) u32_g;
typedef u32 __attribute__((address_space(3))) u32_s;

__device__ __forceinline__ void load16_lds(const void* g, void* s) {
    // async global->LDS, 16B per lane; LDS dest = wave-uniform base + lane*16
    __builtin_amdgcn_global_load_lds((u32_g*)g, (u32_s*)s, 16, 0, 0);
}

// ---------------- 1. per-block max|kernel| (no atomics, no memset) ----------------
__global__ void maxabs_kernel(const float* __restrict__ w, float* __restrict__ blockmax, int n4) {
    __shared__ float sm[4];
    int i = blockIdx.x * blockDim.x + threadIdx.x;
    int stride = gridDim.x * blockDim.x;
    float m = 0.f;
    for (; i < n4; i += stride) {
        float4 v = ((const float4*)w)[i];
        m = fmaxf(m, fmaxf(fmaxf(fabsf(v.x), fabsf(v.y)), fmaxf(fabsf(v.z), fabsf(v.w))));
    }
#pragma unroll
    for (int off = 32; off > 0; off >>= 1)
        m = fmaxf(m, __shfl_down(m, off, 64));
    int lane = threadIdx.x & 63, wave = threadIdx.x >> 6;
    if (lane == 0) sm[wave] = m;
    __syncthreads();
    if (threadIdx.x == 0)
        blockmax[blockIdx.x] = fmaxf(fmaxf(sm[0], sm[1]), fmaxf(sm[2], sm[3]));
}

// ---------------- 2. W_eff^T (N x K, bf16) = quant-dequant(kernel) + a@b ----------------
__global__ void build_w_kernel(const float* __restrict__ kern, const float* __restrict__ amat,
                               const float* __restrict__ bmat, const float* __restrict__ blockmax,
                               __bf16* __restrict__ wt) {
    __shared__ float smax;
    if (threadIdx.x < 64) {
        float m = 0.f;
#pragma unroll
        for (int j = 0; j < 4; ++j) m = fmaxf(m, blockmax[threadIdx.x + j * 64]);
#pragma unroll
        for (int off = 32; off > 0; off >>= 1)
            m = fmaxf(m, __shfl_down(m, off, 64));
        if (threadIdx.x == 0) smax = m;
    }
    __syncthreads();
    float scale = smax * (1.0f / 7.0f);

    int t = blockIdx.x * blockDim.x + threadIdx.x;   // 0 .. 1M-1
    int k = t & (K_DIM - 1);
    int n = t >> 10;
    float w = kern[k * N_DIM + n];
    float q = rintf(w / scale);                      // RNE == jnp.round
    q = fminf(fmaxf(q, -8.f), 7.f);
    float acc = q * scale;
#pragma unroll
    for (int r = 0; r < 16; ++r)
        acc += amat[k * 16 + r] * bmat[r * N_DIM + n];
    wt[(size_t)n * K_DIM + k] = (__bf16)acc;
}

// ---------------- 3. x fp32 -> bf16 ----------------
__global__ void cvt_x_kernel(const float4* __restrict__ x, bf16x8* __restrict__ xb, int n8) {
    int i = blockIdx.x * blockDim.x + threadIdx.x;
    if (i >= n8) return;
    float4 v0 = x[i * 2];
    float4 v1 = x[i * 2 + 1];
    bf16x8 o;
    o[0] = (__bf16)v0.x; o[1] = (__bf16)v0.y; o[2] = (__bf16)v0.z; o[3] = (__bf16)v0.w;
    o[4] = (__bf16)v1.x; o[5] = (__bf16)v1.y; o[6] = (__bf16)v1.z; o[7] = (__bf16)v1.w;
    xb[i] = o;
}

// ---------------- 4. pipelined GEMM: out[M,N] = A[M,K] * Wt[N,K]^T + bias ----------------
// 256x256 tile, BK=32, 8 waves (2M x 4N), 4-deep circular LDS pipeline.
// Staging: global_load_lds width 16, linear LDS dest; conflict-free read swizzle
//   physical_chunk = logical_chunk ^ ((row>>1)&3)  (2 lanes per 16B slot -> free).
// Sync: ONE s_barrier per K-tile; counted s_waitcnt vmcnt(8) (never 0 in main
// loop) keeps 2 tiles of global_load_lds in flight across the barrier.
// Race-freedom: in iter t we stage tile t+3 into buffer (t+3)%4 == (t-1)%4; all
// waves finished reading tile t-1 before passing this iter's barrier (their
// ds_reads were consumed by MFMAs issued before the barrier).
__global__ __launch_bounds__(512, 2)
void gemm256_kernel(const __bf16* __restrict__ xb, const __bf16* __restrict__ wt,
                    const float* __restrict__ bias, float* __restrict__ out) {
    __shared__ __attribute__((aligned(16))) __bf16 As[PDEPTH][BM2 * BK2];
    __shared__ __attribute__((aligned(16))) __bf16 Bs[PDEPTH][BN2 * BK2];

    const int tid  = threadIdx.x;
    const int lane = tid & 63;
    const int wave = tid >> 6;          // 0..7
    const int wr   = wave >> 2;         // 0..1 (M half)
    const int wc   = wave & 3;          // 0..3 (N quarter)
    const int l15  = lane & 15;
    const int l4   = lane >> 4;

    // XCD swizzle: 512 blocks; xcd = lb&7; ib = lb>>3; n_tile = ib&3;
    // m_panel = (ib>>2)*8 + xcd  -> all 4 N-tiles of an M-panel share one XCD.
    const int lb  = blockIdx.x;
    const int ib  = lb >> 3;
    const int bn0 = (ib & 3) * BN2;
    const int bm0 = (((ib >> 2) << 3) | (lb & 7)) * BM2;

    // staging geometry: one gload_lds = 16 rows x 64B; lane l -> row base+(l>>2),
    // physical chunk l&3; source pre-swizzled so LDS[row][pc] holds k-chunk pc^((row>>1)&3)
    const int srow = lane >> 2;                        // 0..15
    const int lc   = (lane & 3) ^ ((srow >> 1) & 3);   // swizzled source chunk

    const __bf16* xg = xb + (size_t)(bm0 + wave * 32 + srow) * K_DIM + lc * 8;
    const __bf16* wg = wt + (size_t)(bn0 + wave * 32 + srow) * K_DIM + lc * 8;
    __bf16* sa = &As[0][wave * 32 * BK2];
    __bf16* sb = &Bs[0][wave * 32 * BK2];

    // compute-read offset within a [row][BK2] tile (swizzled, 16B aligned)
    const int ro = l15 * BK2 + ((l4 ^ ((l15 >> 1) & 3)) << 3);

    f32x4 acc[8][4] = {};

#define STAGE2(T) do {                                                     \
        const int b_ = (T) & (PDEPTH - 1); const int k_ = (T) * BK2;       \
        load16_lds(xg + k_,              sa + b_ * (BM2 * BK2));           \
        load16_lds(xg + 16 * K_DIM + k_, sa + b_ * (BM2 * BK2) + 16 * BK2);\
        load16_lds(wg + k_,              sb + b_ * (BN2 * BK2));           \
        load16_lds(wg + 16 * K_DIM + k_, sb + b_ * (BN2 * BK2) + 16 * BK2);\
    } while (0)

    STAGE2(0); STAGE2(1); STAGE2(2);

#pragma unroll 4
    for (int t = 0; t < NT2; ++t) {
        // counted waits: tile t landed iff all but the newest 8 loads retired
        if (t < NT2 - 2)       asm volatile("s_waitcnt vmcnt(8)" ::: "memory");
        else if (t == NT2 - 2) asm volatile("s_waitcnt vmcnt(4)" ::: "memory");
        else                   asm volatile("s_waitcnt vmcnt(0)" ::: "memory");
        __builtin_amdgcn_s_barrier();
        __builtin_amdgcn_sched_barrier(0);

        if (t + 3 < NT2) STAGE2(t + 3);   // -> buffer of tile t-1 (reads done)

        const __bf16* ap = (const __bf16*)As + (t & (PDEPTH - 1)) * (BM2 * BK2)
                           + wr * (128 * BK2) + ro;
        const __bf16* bp = (const __bf16*)Bs + (t & (PDEPTH - 1)) * (BN2 * BK2)
                           + wc * (64 * BK2) + ro;
        bf16x8 af[8], bv[4];
#pragma unroll
        for (int nt = 0; nt < 4; ++nt) bv[nt] = *(const bf16x8*)(bp + nt * (16 * BK2));
#pragma unroll
        for (int mt = 0; mt < 8; ++mt) af[mt] = *(const bf16x8*)(ap + mt * (16 * BK2));
        __builtin_amdgcn_s_setprio(1);
#pragma unroll
        for (int mt = 0; mt < 8; ++mt)
#pragma unroll
            for (int nt = 0; nt < 4; ++nt)
                acc[mt][nt] = __builtin_amdgcn_mfma_f32_16x16x32_bf16(
                    af[mt], bv[nt], acc[mt][nt], 0, 0, 0);
        __builtin_amdgcn_s_setprio(0);
    }
#undef STAGE2

    // ---- epilogue: C/D layout col = lane&15, row = (lane>>4)*4 + reg ----
#pragma unroll
    for (int nt = 0; nt < 4; ++nt) {
        int n = bn0 + wc * 64 + nt * 16 + l15;
        float bvs = bias[n];
#pragma unroll
        for (int mt = 0; mt < 8; ++mt) {
            int m = bm0 + wr * 128 + mt * 16 + l4 * 4;
            float* op = out + (size_t)m * N_DIM + n;
#pragma unroll
            for (int r = 0; r < 4; ++r)
                op[(size_t)r * N_DIM] = acc[mt][nt][r] + bvs;
        }
    }
}

// ---------------- 4b. fallback GEMM (fp32 A, reg-staged), 128x128 ----------------
__global__ __launch_bounds__(256, 4)
void gemm_fb_kernel(const float* __restrict__ x, const __bf16* __restrict__ wt,
                    const float* __restrict__ bias, float* __restrict__ out) {
    __shared__ __attribute__((aligned(16))) __bf16 As[BM * BK];
    __shared__ __attribute__((aligned(16))) __bf16 Bs[BN * BK];

    const int tid  = threadIdx.x;
    const int lane = tid & 63;
    const int wave = tid >> 6;
    const int wm = (wave >> 1) * 64;
    const int wn = (wave & 1) * 64;

    const int l = blockIdx.x;
    const int i = l >> 3;
    const int bn0 = (i & 7) * BN;
    const int bm0 = (((i >> 3) << 3) | (l & 7)) * BM;

    const int l15 = lane & 15;
    const int l4  = lane >> 4;

    f32x4 acc[4][4] = {};

    const int srow = lane >> 3;
    const int gch  = (lane & 7) ^ srow;

    for (int k0 = 0; k0 < K_DIM; k0 += BK) {
        __syncthreads();
#pragma unroll
        for (int j = 0; j < 4; ++j) {
            int r = j * 32 + wave * 8;
            const __bf16* g = wt + (size_t)(bn0 + r + srow) * K_DIM + k0 + gch * 8;
            load16_lds(g, &Bs[r * BK]);
        }
#pragma unroll
        for (int j = 0; j < 8; ++j) {
            int f  = j * 256 + tid;
            int r  = f >> 4;
            int c4 = f & 15;
            float4 v = *(const float4*)(x + (size_t)(bm0 + r) * K_DIM + k0 + c4 * 4);
            int p = (c4 >> 1) ^ (r & 7);
            bf16x4 o;
            o.x = (__bf16)v.x; o.y = (__bf16)v.y; o.z = (__bf16)v.z; o.w = (__bf16)v.w;
            *(bf16x4*)(&As[r * BK + p * 8 + (c4 & 1) * 4]) = o;
        }
        __syncthreads();

#pragma unroll
        for (int ks = 0; ks < 2; ++ks) {
            bf16x8 af[4], bfr[4];
#pragma unroll
            for (int mt = 0; mt < 4; ++mt) {
                int r = wm + mt * 16 + l15;
                int p = (ks * 4 + l4) ^ (r & 7);
                af[mt] = *(const bf16x8*)(&As[r * BK + p * 8]);
            }
#pragma unroll
            for (int nt = 0; nt < 4; ++nt) {
                int r = wn + nt * 16 + l15;
                int p = (ks * 4 + l4) ^ (r & 7);
                bfr[nt] = *(const bf16x8*)(&Bs[r * BK + p * 8]);
            }
#pragma unroll
            for (int mt = 0; mt < 4; ++mt)
#pragma unroll
                for (int nt = 0; nt < 4; ++nt)
                    acc[mt][nt] = __builtin_amdgcn_mfma_f32_16x16x32_bf16(
                        af[mt], bfr[nt], acc[mt][nt], 0, 0, 0);
        }
    }

#pragma unroll
    for (int nt = 0; nt < 4; ++nt) {
        int n = bn0 + wn + nt * 16 + l15;
        float bv = bias[n];
#pragma unroll
        for (int mt = 0; mt < 4; ++mt) {
            int m = bm0 + wm + mt * 16 + l4 * 4;
            float* op = out + (size_t)m * N_DIM + n;
#pragma unroll
            for (int r = 0; r < 4; ++r)
                op[(size_t)r * N_DIM] = acc[mt][nt][r] + bv;
        }
    }
}

extern "C" void kernel_launch(void* const* d_in, const int* in_sizes, int n_in,
                              void* d_out, int out_size, void* d_ws, size_t ws_size,
                              hipStream_t stream) {
    const float* x    = (const float*)d_in[0];
    const float* kern = (const float*)d_in[1];
    const float* bias = (const float*)d_in[2];
    const float* amat = (const float*)d_in[3];
    const float* bmat = (const float*)d_in[4];
    float* out = (float*)d_out;
    const int M = in_sizes[0] / K_DIM;   // 32768

    float* blockmax = (float*)d_ws;                          // 256 floats
    __bf16* wt = (__bf16*)((char*)d_ws + 4096);
    const size_t xb_off    = 4096 + (size_t)N_DIM * K_DIM * sizeof(__bf16);
    const size_t need_fast = xb_off + (size_t)M * K_DIM * sizeof(__bf16);

    maxabs_kernel<<<256, 256, 0, stream>>>(kern, blockmax, K_DIM * N_DIM / 4);
    build_w_kernel<<<K_DIM * N_DIM / 256, 256, 0, stream>>>(kern, amat, bmat, blockmax, wt);

    // fast path needs ws for xb and M divisible by 256*8 (panel-swizzle bijectivity)
    if (ws_size >= need_fast && (M % (BM2 * 8)) == 0) {
        __bf16* xbuf = (__bf16*)((char*)d_ws + xb_off);
        int n8 = M * K_DIM / 8;
        cvt_x_kernel<<<(n8 + 255) / 256, 256, 0, stream>>>((const float4*)x, (bf16x8*)xbuf, n8);
        gemm256_kernel<<<(M / BM2) * (N_DIM / BN2), 512, 0, stream>>>(xbuf, wt, bias, out);
    } else {
        gemm_fb_kernel<<<(M / BM) * (N_DIM / BN), 256, 0, stream>>>(x, wt, bias, out);
    }
}